// Round 2
// baseline (4250.526 us; speedup 1.0000x reference)
//
#include <hip/hip_runtime.h>
#include <math.h>

// ---------------------------------------------------------------------------
// RSSM: B=16, T=64 (bt=1024), encoder 3->32->64->128->256 (k4 s2 p1) with
// full-tensor LayerNorm+SiLU per layer, fc 4096->256, GRU(1030->128),
// prior 128->1024, post 384->1024, z = per-32-chunk argmax one-hot.
// All fp32: argmax feeds back into the recurrence; one flipped argmax = 1.0
// error in z (threshold 0.024) -> low precision in the logit path is fatal.
// Encoder is chunked over samples so the workspace footprint adapts to
// ws_size (C=16 worst case needs ~21 MB). LN+SiLU fused into conv2/3/4
// (one block per sample owns the whole tensor needed for LN stats).
// ---------------------------------------------------------------------------

__device__ __forceinline__ float silu_f(float t){ return t / (1.f + __expf(-t)); }
__device__ __forceinline__ float sigm_f(float x){ return 1.f / (1.f + expf(-x)); }

// Block-level mean/rstd over m values; each thread contributes (s, s2).
// 256-thread blocks (4 waves).
__device__ __forceinline__ void block_stats_256(float s, float s2, int m,
                                                float& mean, float& rstd)
{
    __shared__ float red[8];
#pragma unroll
    for (int off = 32; off > 0; off >>= 1) {
        s  += __shfl_down(s, off);
        s2 += __shfl_down(s2, off);
    }
    int wv = threadIdx.x >> 6;
    if ((threadIdx.x & 63) == 0) { red[wv] = s; red[4 + wv] = s2; }
    __syncthreads();
    if (threadIdx.x == 0) {
        float S  = (red[0] + red[1]) + (red[2] + red[3]);
        float S2 = (red[4] + red[5]) + (red[6] + red[7]);
        float mu = S / m;
        float var = S2 / m - mu * mu;
        red[0] = mu;
        red[1] = rsqrtf(var + 1e-5f);
    }
    __syncthreads();
    mean = red[0]; rstd = red[1];
}

// ------------------------- conv1: 3x64x64 -> 32x32x32 ----------------------
__global__ __launch_bounds__(256) void conv1_k(const float* __restrict__ in,
    const float* __restrict__ w, const float* __restrict__ bias, float* __restrict__ out)
{
    int n  = blockIdx.x;                 // chunk-local sample
    int yq = blockIdx.y;                 // 4 y-quarters
    int tx = threadIdx.x & 31;
    int ty = threadIdx.x >> 5;           // 0..7
    int y  = yq * 8 + ty;                // 0..31
    const float* ip = in + (size_t)n * 12288;

    float okf[16]; int offs[16];
#pragma unroll
    for (int ky = 0; ky < 4; ky++) {
        int yy = 2 * y - 1 + ky;
        bool yok = ((unsigned)yy < 64u);
#pragma unroll
        for (int kx = 0; kx < 4; kx++) {
            int xx = 2 * tx - 1 + kx;
            bool ok = yok && ((unsigned)xx < 64u);
            okf[ky*4+kx]  = ok ? 1.f : 0.f;
            offs[ky*4+kx] = ok ? yy * 64 + xx : 0;
        }
    }
    float iv[48];
#pragma unroll
    for (int c = 0; c < 3; c++)
#pragma unroll
        for (int q = 0; q < 16; q++)
            iv[c*16+q] = ip[c*4096 + offs[q]] * okf[q];

    float* op = out + (size_t)n * 32768 + y * 32 + tx;
    for (int oc = 0; oc < 32; oc++) {           // oc uniform -> weights s_load
        float acc = bias[oc];
        const float* wp = w + oc * 48;
#pragma unroll
        for (int q = 0; q < 48; q++) acc += iv[q] * wp[q];
        op[oc * 1024] = acc;
    }
}

// LN1 stats (conv1 output spans 4 blocks/sample -> separate pass)
__global__ __launch_bounds__(256) void ln_stats_k(const float* __restrict__ x,
                                                  float* __restrict__ mv, int m)
{
    int n = blockIdx.x;
    const float* p = x + (size_t)n * m;
    float s = 0.f, s2 = 0.f;
    for (int i = threadIdx.x * 4; i < m; i += 1024) {
        float4 v = *(const float4*)(p + i);
        s  += (v.x + v.y) + (v.z + v.w);
        s2 += (v.x*v.x + v.y*v.y) + (v.z*v.z + v.w*v.w);
    }
#pragma unroll
    for (int off = 32; off > 0; off >>= 1) {
        s  += __shfl_down(s, off);
        s2 += __shfl_down(s2, off);
    }
    __shared__ float ls[4], ls2[4];
    int wv = threadIdx.x >> 6;
    if ((threadIdx.x & 63) == 0) { ls[wv] = s; ls2[wv] = s2; }
    __syncthreads();
    if (threadIdx.x == 0) {
        float S  = (ls[0] + ls[1]) + (ls[2] + ls[3]);
        float S2 = (ls2[0] + ls2[1]) + (ls2[2] + ls2[3]);
        float mean = S / m;
        float var  = S2 / m - mean * mean;
        mv[n * 2]     = mean;
        mv[n * 2 + 1] = rsqrtf(var + 1e-5f);
    }
}

__global__ __launch_bounds__(256) void ln_apply_k(float* __restrict__ x,
    const float* __restrict__ mv, const float* __restrict__ g,
    const float* __restrict__ b, int m)
{
    int n = blockIdx.y;
    int i = (blockIdx.x * 256 + threadIdx.x) * 4;
    float mean = mv[n * 2], rstd = mv[n * 2 + 1];
    float* px = x + (size_t)n * m + i;
    float4 v  = *(float4*)px;
    float4 gv = *(const float4*)(g + i);
    float4 bv = *(const float4*)(b + i);
    v.x = silu_f((v.x - mean) * rstd * gv.x + bv.x);
    v.y = silu_f((v.y - mean) * rstd * gv.y + bv.y);
    v.z = silu_f((v.z - mean) * rstd * gv.z + bv.z);
    v.w = silu_f((v.w - mean) * rstd * gv.w + bv.w);
    *(float4*)px = v;
}

// ----------------- conv2 + LN2 + SiLU: 32x32x32 -> 64x16x16 ----------------
// one block per sample; thread = spatial pos, acc[64] = all output channels
__global__ __launch_bounds__(256) void conv2_f(const float* __restrict__ in,
    const float* __restrict__ w, const float* __restrict__ bias,
    const float* __restrict__ g, const float* __restrict__ bet, float* __restrict__ out)
{
    int n  = blockIdx.x;
    int tid = threadIdx.x;
    int tx = tid & 15, ty = tid >> 4;
    const float* ip = in + (size_t)n * 32768;

    float okf[16]; int offs[16];
#pragma unroll
    for (int ky = 0; ky < 4; ky++) {
        int yy = 2 * ty - 1 + ky;
        bool yok = ((unsigned)yy < 32u);
#pragma unroll
        for (int kx = 0; kx < 4; kx++) {
            int xx = 2 * tx - 1 + kx;
            bool ok = yok && ((unsigned)xx < 32u);
            okf[ky*4+kx]  = ok ? 1.f : 0.f;
            offs[ky*4+kx] = ok ? yy * 32 + xx : 0;
        }
    }
    float acc[64];
#pragma unroll
    for (int i = 0; i < 64; i++) acc[i] = bias[i];
    for (int c = 0; c < 32; c++) {
        const float* icp = ip + c * 1024;
        float iv[16];
#pragma unroll
        for (int q = 0; q < 16; q++) iv[q] = icp[offs[q]] * okf[q];
        for (int i = 0; i < 64; i++) {
            const float* wp = w + ((size_t)i * 32 + c) * 16;   // uniform -> s_load
#pragma unroll
            for (int q = 0; q < 16; q++) acc[i] += iv[q] * wp[q];
        }
    }
    float s = 0.f, s2 = 0.f;
#pragma unroll
    for (int i = 0; i < 64; i++) { s += acc[i]; s2 += acc[i] * acc[i]; }
    float mean, rstd;
    block_stats_256(s, s2, 16384, mean, rstd);

    float* op = out + (size_t)n * 16384;
    for (int i = 0; i < 64; i++) {
        int flat = i * 256 + tid;
        float v = (acc[i] - mean) * rstd * g[flat] + bet[flat];
        op[flat] = silu_f(v);
    }
}

// ----------------- conv3 + LN3 + SiLU: 64x16x16 -> 128x8x8 -----------------
__global__ __launch_bounds__(256) void conv3_f(const float* __restrict__ in,
    const float* __restrict__ w, const float* __restrict__ bias,
    const float* __restrict__ g, const float* __restrict__ bet, float* __restrict__ out)
{
    int n   = blockIdx.x;
    int tid = threadIdx.x;
    int ocq = __builtin_amdgcn_readfirstlane(tid >> 6);  // wave id 0..3
    int s0 = tid & 63, y = s0 >> 3, x = s0 & 7;
    const float* ip = in + (size_t)n * 16384;

    float okf[16]; int offs[16];
#pragma unroll
    for (int ky = 0; ky < 4; ky++) {
        int yy = 2 * y - 1 + ky;
        bool yok = ((unsigned)yy < 16u);
#pragma unroll
        for (int kx = 0; kx < 4; kx++) {
            int xx = 2 * x - 1 + kx;
            bool ok = yok && ((unsigned)xx < 16u);
            okf[ky*4+kx]  = ok ? 1.f : 0.f;
            offs[ky*4+kx] = ok ? yy * 16 + xx : 0;
        }
    }
    float acc[32];
#pragma unroll
    for (int i = 0; i < 32; i++) acc[i] = bias[ocq * 32 + i];
    for (int c = 0; c < 64; c++) {
        const float* icp = ip + c * 256;
        float iv[16];
#pragma unroll
        for (int q = 0; q < 16; q++) iv[q] = icp[offs[q]] * okf[q];
        for (int i = 0; i < 32; i++) {
            const float* wp = w + ((size_t)(ocq * 32 + i) * 64 + c) * 16;  // wave-uniform
#pragma unroll
            for (int q = 0; q < 16; q++) acc[i] += iv[q] * wp[q];
        }
    }
    float s = 0.f, s2 = 0.f;
#pragma unroll
    for (int i = 0; i < 32; i++) { s += acc[i]; s2 += acc[i] * acc[i]; }
    float mean, rstd;
    block_stats_256(s, s2, 8192, mean, rstd);

    float* op = out + (size_t)n * 8192;
    for (int i = 0; i < 32; i++) {
        int flat = (ocq * 32 + i) * 64 + s0;
        float v = (acc[i] - mean) * rstd * g[flat] + bet[flat];
        op[flat] = silu_f(v);
    }
}

// ----------------- conv4 + LN4 + SiLU: 128x8x8 -> 256x4x4 ------------------
// thread = output channel; whole input channel read via uniform scalar loads
__global__ __launch_bounds__(256) void conv4_f(const float* __restrict__ in,
    const float* __restrict__ w, const float* __restrict__ bias,
    const float* __restrict__ g, const float* __restrict__ bet, float* __restrict__ out)
{
    int n  = blockIdx.x;
    int oc = threadIdx.x;                 // 0..255
    const float* ip = in + (size_t)n * 8192;
    const float* wr = w + (size_t)oc * 2048;

    float acc[16];
#pragma unroll
    for (int s = 0; s < 16; s++) acc[s] = bias[oc];

    for (int c = 0; c < 128; c++) {
        const float* ic = ip + c * 64;     // uniform base -> s_load, CSE'd
        const float* wc = wr + c * 16;
        float wf[16];
#pragma unroll
        for (int q = 0; q < 16; q += 4) {
            float4 v = *(const float4*)(wc + q);
            wf[q] = v.x; wf[q+1] = v.y; wf[q+2] = v.z; wf[q+3] = v.w;
        }
#pragma unroll
        for (int y = 0; y < 4; y++)
#pragma unroll
        for (int x = 0; x < 4; x++) {
            float a = acc[y * 4 + x];
#pragma unroll
            for (int ky = 0; ky < 4; ky++) {
                int yy = 2 * y - 1 + ky;
                if (yy < 0 || yy > 7) continue;      // folds at compile time
#pragma unroll
                for (int kx = 0; kx < 4; kx++) {
                    int xx = 2 * x - 1 + kx;
                    if (xx < 0 || xx > 7) continue;
                    a += wf[ky * 4 + kx] * ic[yy * 8 + xx];
                }
            }
            acc[y * 4 + x] = a;
        }
    }
    float s = 0.f, s2 = 0.f;
#pragma unroll
    for (int q = 0; q < 16; q++) { s += acc[q]; s2 += acc[q] * acc[q]; }
    float mean, rstd;
    block_stats_256(s, s2, 4096, mean, rstd);

    float* op = out + (size_t)n * 4096;
#pragma unroll
    for (int q = 0; q < 16; q++) {
        int flat = oc * 16 + q;
        float v = (acc[q] - mean) * rstd * g[flat] + bet[flat];
        op[flat] = silu_f(v);
    }
}

// ------------------------- fc: [S,4096] @ [256,4096]^T ---------------------
__global__ __launch_bounds__(256) void fc_k(const float* __restrict__ a,
    const float* __restrict__ w, const float* __restrict__ bias, float* __restrict__ o)
{
    int n0 = blockIdx.x * 8;              // chunk-local rows
    int j  = threadIdx.x;
    float acc[8];
#pragma unroll
    for (int r = 0; r < 8; r++) acc[r] = 0.f;
    const float* wr = w + (size_t)j * 4096;
    for (int k = 0; k < 4096; k += 4) {
        float4 wv = *(const float4*)(wr + k);
#pragma unroll
        for (int r = 0; r < 8; r++) {
            const float* ar = a + (size_t)(n0 + r) * 4096 + k;   // uniform -> s_load
            acc[r] += wv.x*ar[0] + wv.y*ar[1] + wv.z*ar[2] + wv.w*ar[3];
        }
    }
    float bj = bias[j];
#pragma unroll
    for (int r = 0; r < 8; r++) o[(size_t)(n0 + r) * 256 + j] = acc[r] + bj;
}

// ----------- Fpost[n,j] = post_b[j] + feats[n,:] @ post_w[j,128:384] -------
__global__ __launch_bounds__(256) void fpost_k(const float* __restrict__ f,
    const float* __restrict__ w, const float* __restrict__ bias, float* __restrict__ o)
{
    int n0 = blockIdx.x * 4;
    int tid = threadIdx.x;
    float acc[4][4];
#pragma unroll
    for (int r = 0; r < 4; r++)
#pragma unroll
        for (int jj = 0; jj < 4; jj++) acc[r][jj] = 0.f;
    for (int k = 0; k < 256; k += 4) {
        float4 wv[4];
#pragma unroll
        for (int jj = 0; jj < 4; jj++)
            wv[jj] = *(const float4*)(w + (size_t)(tid + jj * 256) * 384 + 128 + k);
#pragma unroll
        for (int r = 0; r < 4; r++) {
            const float* fr = f + (size_t)(n0 + r) * 256 + k;    // uniform
            float a0 = fr[0], a1 = fr[1], a2 = fr[2], a3 = fr[3];
#pragma unroll
            for (int jj = 0; jj < 4; jj++)
                acc[r][jj] += wv[jj].x*a0 + wv[jj].y*a1 + wv[jj].z*a2 + wv[jj].w*a3;
        }
    }
#pragma unroll
    for (int jj = 0; jj < 4; jj++) {
        float bj = bias[tid + jj * 256];
#pragma unroll
        for (int r = 0; r < 4; r++)
            o[(size_t)(n0 + r) * 1024 + tid + jj * 256] = acc[r][jj] + bj;
    }
}

// ----------- prior[n,j] = prior_b[j] + h[n,:] @ prior_w[j,:] ---------------
__global__ __launch_bounds__(256) void prior_k(const float* __restrict__ h,
    const float* __restrict__ w, const float* __restrict__ bias, float* __restrict__ o)
{
    int n0 = blockIdx.x * 4;
    int tid = threadIdx.x;
    float acc[4][4];
#pragma unroll
    for (int r = 0; r < 4; r++)
#pragma unroll
        for (int jj = 0; jj < 4; jj++) acc[r][jj] = 0.f;
    for (int k = 0; k < 128; k += 4) {
        float4 wv[4];
#pragma unroll
        for (int jj = 0; jj < 4; jj++)
            wv[jj] = *(const float4*)(w + (size_t)(tid + jj * 256) * 128 + k);
#pragma unroll
        for (int r = 0; r < 4; r++) {
            const float* hr = h + (size_t)(n0 + r) * 128 + k;    // uniform
            float a0 = hr[0], a1 = hr[1], a2 = hr[2], a3 = hr[3];
#pragma unroll
            for (int jj = 0; jj < 4; jj++)
                acc[r][jj] += wv[jj].x*a0 + wv[jj].y*a1 + wv[jj].z*a2 + wv[jj].w*a3;
        }
    }
#pragma unroll
    for (int jj = 0; jj < 4; jj++) {
        float bj = bias[tid + jj * 256];
#pragma unroll
        for (int r = 0; r < 4; r++)
            o[(size_t)(n0 + r) * 1024 + tid + jj * 256] = acc[r][jj] + bj;
    }
}

// ----------- Ai[n,j] = bih[j] + actions[n,:] @ wih[j,1024:1030] ------------
__global__ __launch_bounds__(128) void ai_k(const float* __restrict__ act,
    const float* __restrict__ wih, const float* __restrict__ bih, float* __restrict__ o)
{
    int n = blockIdx.x;
    int j = blockIdx.y * 128 + threadIdx.x;     // 0..383
    const float* ar = act + (size_t)n * 6;       // uniform
    const float* wr = wih + (size_t)j * 1030 + 1024;
    float acc = bih[j];
#pragma unroll
    for (int k = 0; k < 6; k++) acc += ar[k] * wr[k];
    o[(size_t)n * 384 + j] = acc;
}

// ----------- wihT[k,j] = wih[j,k]  (z-part only, k<1024) -------------------
__global__ __launch_bounds__(256) void tr_k(const float* __restrict__ wih,
                                            float* __restrict__ wt)
{
    int g = blockIdx.x * 256 + threadIdx.x;      // 0..393215
    int k = g / 384;
    int j = g - k * 384;
    wt[g] = wih[(size_t)j * 1030 + k];
}

// ------------------------- GRU recurrence (1 block / sample) ---------------
__global__ __launch_bounds__(1024) void gru_k(const float* __restrict__ wihT,
    const float* __restrict__ whh, const float* __restrict__ bhh,
    const float* __restrict__ ai, const float* __restrict__ fpost,
    const float* __restrict__ postw, float* __restrict__ out)
{
    float* out_post = out + 1048576;
    float* out_h    = out + 2097152;
    float* out_z    = out + 2228224;
    int b   = blockIdx.x;
    int tid = threadIdx.x;
    __shared__ __align__(16) float h[128];
    __shared__ float gi[384], gh[384], p[1024];
    __shared__ int idx[32];
    if (tid < 128) h[tid] = 0.f;
    __syncthreads();

    for (int t = 0; t < 64; t++) {
        int n = b * 64 + t;
        if (tid < 384) {
            float a = ai[(size_t)n * 384 + tid];
            if (t > 0) {
#pragma unroll 8
                for (int c = 0; c < 32; c++)
                    a += wihT[(size_t)(c * 32 + idx[c]) * 384 + tid];
            }
            gi[tid] = a;
            float a2 = bhh[tid];
            const float* wr = whh + (size_t)tid * 128;
#pragma unroll
            for (int k = 0; k < 128; k += 4) {
                float4 wv = *(const float4*)(wr + k);
                float4 hv = *(const float4*)(h + k);
                a2 += wv.x*hv.x + wv.y*hv.y + wv.z*hv.z + wv.w*hv.w;
            }
            gh[tid] = a2;
        }
        __syncthreads();                                    // B1
        if (tid < 128) {
            float r  = sigm_f(gi[tid] + gh[tid]);
            float u  = sigm_f(gi[128 + tid] + gh[128 + tid]);
            float nn = tanhf(gi[256 + tid] + r * gh[256 + tid]);
            float hn = (1.f - u) * nn + u * h[tid];
            h[tid] = hn;
            out_h[(size_t)n * 128 + tid] = hn;
        }
        __syncthreads();                                    // B2
        {
            float a = fpost[(size_t)n * 1024 + tid];
            const float* wr = postw + (size_t)tid * 384;
#pragma unroll
            for (int k = 0; k < 128; k += 4) {
                float4 wv = *(const float4*)(wr + k);
                float4 hv = *(const float4*)(h + k);
                a += wv.x*hv.x + wv.y*hv.y + wv.z*hv.z + wv.w*hv.w;
            }
            p[tid] = a;
            out_post[(size_t)n * 1024 + tid] = a;
        }
        __syncthreads();                                    // B3
        if (tid < 32) {
            const float* pc = p + tid * 32;
            float best = pc[0]; int bi = 0;
#pragma unroll
            for (int q = 1; q < 32; q++) {
                float v = pc[q];
                if (v > best) { best = v; bi = q; }         // first-max = np.argmax
            }
            idx[tid] = bi;
        }
        __syncthreads();                                    // B4
        out_z[(size_t)n * 1024 + tid] = ((tid & 31) == idx[tid >> 5]) ? 1.f : 0.f;
    }
}

// ---------------------------------------------------------------------------
extern "C" void kernel_launch(void* const* d_in, const int* in_sizes, int n_in,
                              void* d_out, int out_size, void* d_ws, size_t ws_size,
                              hipStream_t stream)
{
    const float* states  = (const float*)d_in[0];
    const float* actions = (const float*)d_in[1];
    const float* c1w = (const float*)d_in[2];  const float* c1b = (const float*)d_in[3];
    const float* l1g = (const float*)d_in[4];  const float* l1b = (const float*)d_in[5];
    const float* c2w = (const float*)d_in[6];  const float* c2b = (const float*)d_in[7];
    const float* l2g = (const float*)d_in[8];  const float* l2b = (const float*)d_in[9];
    const float* c3w = (const float*)d_in[10]; const float* c3b = (const float*)d_in[11];
    const float* l3g = (const float*)d_in[12]; const float* l3b = (const float*)d_in[13];
    const float* c4w = (const float*)d_in[14]; const float* c4b = (const float*)d_in[15];
    const float* l4g = (const float*)d_in[16]; const float* l4b = (const float*)d_in[17];
    const float* fcw = (const float*)d_in[18]; const float* fcb = (const float*)d_in[19];
    const float* wih = (const float*)d_in[20]; const float* whh = (const float*)d_in[21];
    const float* bih = (const float*)d_in[22]; const float* bhh = (const float*)d_in[23];
    const float* prw = (const float*)d_in[24]; const float* prb = (const float*)d_in[25];
    const float* pw  = (const float*)d_in[26]; const float* pb  = (const float*)d_in[27];

    float* out = (float*)d_out;
    float* ws  = (float*)d_ws;

    // ---- adaptive chunking: largest S whose footprint fits ws_size --------
    // footprint = (S*32768 + S*16384 + S*2 + 2,097,152) floats
    size_t S = 64;
    {
        const size_t cands[4] = {1024, 512, 256, 128};
        for (int i = 0; i < 4; i++) {
            size_t need = (cands[i] * 49154ull + 2097152ull) * 4ull;
            if (need <= ws_size) { S = cands[i]; break; }
        }
    }
    int C = (int)(1024 / S);

    float* bufA  = ws;                       // S*32768
    float* bufB  = bufA + S * 32768;         // S*16384
    float* mv    = bufB + S * 16384;         // S*2
    float* feats = mv + S * 2;               // 262,144
    float* fpost = feats + 262144;           // 1,048,576
    float* aibuf = fpost + 1048576;          //   393,216
    float* wihT  = aibuf + 393216;           //   393,216

    for (int cc = 0; cc < C; cc++) {
        size_t n0 = (size_t)cc * S;
        conv1_k<<<dim3((unsigned)S, 4), 256, 0, stream>>>(states + n0 * 12288, c1w, c1b, bufA);
        ln_stats_k<<<(unsigned)S, 256, 0, stream>>>(bufA, mv, 32768);
        ln_apply_k<<<dim3(32, (unsigned)S), 256, 0, stream>>>(bufA, mv, l1g, l1b, 32768);
        conv2_f<<<(unsigned)S, 256, 0, stream>>>(bufA, c2w, c2b, l2g, l2b, bufB);
        conv3_f<<<(unsigned)S, 256, 0, stream>>>(bufB, c3w, c3b, l3g, l3b, bufA);
        conv4_f<<<(unsigned)S, 256, 0, stream>>>(bufA, c4w, c4b, l4g, l4b, bufB);
        fc_k<<<(unsigned)(S / 8), 256, 0, stream>>>(bufB, fcw, fcb, feats + n0 * 256);
    }

    fpost_k<<<256, 256, 0, stream>>>(feats, pw, pb, fpost);
    ai_k<<<dim3(1024, 3), 128, 0, stream>>>(actions, wih, bih, aibuf);
    tr_k<<<1536, 256, 0, stream>>>(wih, wihT);

    gru_k<<<16, 1024, 0, stream>>>(wihT, whh, bhh, aibuf, fpost, pw, out);
    prior_k<<<256, 256, 0, stream>>>(out + 2097152, prw, prb, out);
}

// Round 3
// 3536.147 us; speedup vs baseline: 1.2020x; 1.2020x over previous
//
#include <hip/hip_runtime.h>
#include <math.h>

// ---------------------------------------------------------------------------
// RSSM: B=16, T=64 (bt=1024), encoder 3->32->64->128->256 (k4 s2 p1) with
// full-tensor LayerNorm+SiLU per layer, fc 4096->256, GRU(1030->128),
// prior 128->1024, post 384->1024, z = per-32-chunk argmax one-hot.
// All fp32: one flipped argmax = 1.0 error in z -> low precision in the
// logit path is fatal.
// R3 changes (from profile): conv2/conv3 register-spill fix (acc[64]/acc[32]
// dynamically-indexed -> scratch at VGPR=72, 1316us). Now oc-passes of
// acc[16], fully static; LN+SiLU in separate fused per-sample kernel.
// fc weights pre-transposed for coalesced access.
// ---------------------------------------------------------------------------

__device__ __forceinline__ float silu_f(float t){ return t / (1.f + __expf(-t)); }
__device__ __forceinline__ float sigm_f(float x){ return 1.f / (1.f + expf(-x)); }

// Block-level mean/rstd over m values; each thread contributes (s, s2).
__device__ __forceinline__ void block_stats_256(float s, float s2, int m,
                                                float& mean, float& rstd)
{
    __shared__ float red[8];
#pragma unroll
    for (int off = 32; off > 0; off >>= 1) {
        s  += __shfl_down(s, off);
        s2 += __shfl_down(s2, off);
    }
    int wv = threadIdx.x >> 6;
    if ((threadIdx.x & 63) == 0) { red[wv] = s; red[4 + wv] = s2; }
    __syncthreads();
    if (threadIdx.x == 0) {
        float S  = (red[0] + red[1]) + (red[2] + red[3]);
        float S2 = (red[4] + red[5]) + (red[6] + red[7]);
        float mu = S / m;
        float var = S2 / m - mu * mu;
        red[0] = mu;
        red[1] = rsqrtf(var + 1e-5f);
    }
    __syncthreads();
    mean = red[0]; rstd = red[1];
}

// ---------------- fused LayerNorm+SiLU, one block per sample ---------------
__global__ __launch_bounds__(256) void ln_fuse_k(float* __restrict__ x,
    const float* __restrict__ g, const float* __restrict__ b, int m)
{
    int n = blockIdx.x;
    float* p = x + (size_t)n * m;
    float s = 0.f, s2 = 0.f;
    for (int i = threadIdx.x * 4; i < m; i += 1024) {
        float4 v = *(const float4*)(p + i);
        s  += (v.x + v.y) + (v.z + v.w);
        s2 += (v.x*v.x + v.y*v.y) + (v.z*v.z + v.w*v.w);
    }
    float mean, rstd;
    block_stats_256(s, s2, m, mean, rstd);
    for (int i = threadIdx.x * 4; i < m; i += 1024) {
        float4 v  = *(float4*)(p + i);
        float4 gv = *(const float4*)(g + i);
        float4 bv = *(const float4*)(b + i);
        v.x = silu_f((v.x - mean) * rstd * gv.x + bv.x);
        v.y = silu_f((v.y - mean) * rstd * gv.y + bv.y);
        v.z = silu_f((v.z - mean) * rstd * gv.z + bv.z);
        v.w = silu_f((v.w - mean) * rstd * gv.w + bv.w);
        *(float4*)(p + i) = v;
    }
}

// ------------------------- conv1: 3x64x64 -> 32x32x32 ----------------------
__global__ __launch_bounds__(256) void conv1_k(const float* __restrict__ in,
    const float* __restrict__ w, const float* __restrict__ bias, float* __restrict__ out)
{
    int n  = blockIdx.x;                 // chunk-local sample
    int yq = blockIdx.y;                 // 4 y-quarters
    int tx = threadIdx.x & 31;
    int ty = threadIdx.x >> 5;           // 0..7
    int y  = yq * 8 + ty;                // 0..31
    const float* ip = in + (size_t)n * 12288;

    float okf[16]; int offs[16];
#pragma unroll
    for (int ky = 0; ky < 4; ky++) {
        int yy = 2 * y - 1 + ky;
        bool yok = ((unsigned)yy < 64u);
#pragma unroll
        for (int kx = 0; kx < 4; kx++) {
            int xx = 2 * tx - 1 + kx;
            bool ok = yok && ((unsigned)xx < 64u);
            okf[ky*4+kx]  = ok ? 1.f : 0.f;
            offs[ky*4+kx] = ok ? yy * 64 + xx : 0;
        }
    }
    float iv[48];
#pragma unroll
    for (int c = 0; c < 3; c++)
#pragma unroll
        for (int q = 0; q < 16; q++)
            iv[c*16+q] = ip[c*4096 + offs[q]] * okf[q];

    float* op = out + (size_t)n * 32768 + y * 32 + tx;
#pragma unroll 4
    for (int oc = 0; oc < 32; oc++) {           // oc uniform -> weights s_load
        float acc = bias[oc];
        const float* wp = w + oc * 48;
#pragma unroll
        for (int q = 0; q < 48; q++) acc += iv[q] * wp[q];
        op[oc * 1024] = acc;
    }
}

// ------------- conv2 raw: 32x32x32 -> 64x16x16, 4 oc-passes of 16 ----------
__global__ __launch_bounds__(256) void conv2_r(const float* __restrict__ in,
    const float* __restrict__ w, const float* __restrict__ bias, float* __restrict__ out)
{
    int n  = blockIdx.x;
    int tid = threadIdx.x;
    int tx = tid & 15, ty = tid >> 4;
    const float* ip = in + (size_t)n * 32768;

    float okf[16]; int offs[16];
#pragma unroll
    for (int ky = 0; ky < 4; ky++) {
        int yy = 2 * ty - 1 + ky;
        bool yok = ((unsigned)yy < 32u);
#pragma unroll
        for (int kx = 0; kx < 4; kx++) {
            int xx = 2 * tx - 1 + kx;
            bool ok = yok && ((unsigned)xx < 32u);
            okf[ky*4+kx]  = ok ? 1.f : 0.f;
            offs[ky*4+kx] = ok ? yy * 32 + xx : 0;
        }
    }
    float* op = out + (size_t)n * 16384 + tid;
#pragma unroll 1
    for (int p = 0; p < 4; p++) {
        float acc[16];
#pragma unroll
        for (int i = 0; i < 16; i++) acc[i] = bias[p * 16 + i];
        for (int c = 0; c < 32; c++) {
            const float* icp = ip + c * 1024;
            float iv[16];
#pragma unroll
            for (int q = 0; q < 16; q++) iv[q] = icp[offs[q]] * okf[q];
#pragma unroll
            for (int i = 0; i < 16; i++) {
                const float* wp = w + (size_t)p * 8192 + i * 512 + c * 16;  // uniform
#pragma unroll
                for (int q = 0; q < 16; q++) acc[i] += iv[q] * wp[q];
            }
        }
#pragma unroll
        for (int i = 0; i < 16; i++) op[(p * 16 + i) * 256] = acc[i];
    }
}

// ------------- conv3 raw: 64x16x16 -> 128x8x8, wave=32oc, 2 passes ---------
__global__ __launch_bounds__(256) void conv3_r(const float* __restrict__ in,
    const float* __restrict__ w, const float* __restrict__ bias, float* __restrict__ out)
{
    int n   = blockIdx.x;
    int tid = threadIdx.x;
    int ocq = __builtin_amdgcn_readfirstlane(tid >> 6);  // wave id 0..3
    int s0 = tid & 63, y = s0 >> 3, x = s0 & 7;
    const float* ip = in + (size_t)n * 16384;

    float okf[16]; int offs[16];
#pragma unroll
    for (int ky = 0; ky < 4; ky++) {
        int yy = 2 * y - 1 + ky;
        bool yok = ((unsigned)yy < 16u);
#pragma unroll
        for (int kx = 0; kx < 4; kx++) {
            int xx = 2 * x - 1 + kx;
            bool ok = yok && ((unsigned)xx < 16u);
            okf[ky*4+kx]  = ok ? 1.f : 0.f;
            offs[ky*4+kx] = ok ? yy * 16 + xx : 0;
        }
    }
    float* op = out + (size_t)n * 8192 + s0;
#pragma unroll 1
    for (int p = 0; p < 2; p++) {
        int ocb = ocq * 32 + p * 16;                     // wave-uniform
        float acc[16];
#pragma unroll
        for (int i = 0; i < 16; i++) acc[i] = bias[ocb + i];
        for (int c = 0; c < 64; c++) {
            const float* icp = ip + c * 256;
            float iv[16];
#pragma unroll
            for (int q = 0; q < 16; q++) iv[q] = icp[offs[q]] * okf[q];
#pragma unroll
            for (int i = 0; i < 16; i++) {
                const float* wp = w + ((size_t)(ocb + i) * 64 + c) * 16;  // wave-uniform
#pragma unroll
                for (int q = 0; q < 16; q++) acc[i] += iv[q] * wp[q];
            }
        }
#pragma unroll
        for (int i = 0; i < 16; i++) op[(ocb + i) * 64] = acc[i];
    }
}

// ----------------- conv4 + LN4 + SiLU: 128x8x8 -> 256x4x4 ------------------
__global__ __launch_bounds__(256) void conv4_f(const float* __restrict__ in,
    const float* __restrict__ w, const float* __restrict__ bias,
    const float* __restrict__ g, const float* __restrict__ bet, float* __restrict__ out)
{
    int n  = blockIdx.x;
    int oc = threadIdx.x;                 // 0..255
    const float* ip = in + (size_t)n * 8192;
    const float* wr = w + (size_t)oc * 2048;

    float acc[16];
#pragma unroll
    for (int s = 0; s < 16; s++) acc[s] = bias[oc];

    for (int c = 0; c < 128; c++) {
        const float* ic = ip + c * 64;     // uniform base -> s_load, CSE'd
        const float* wc = wr + c * 16;
        float wf[16];
#pragma unroll
        for (int q = 0; q < 16; q += 4) {
            float4 v = *(const float4*)(wc + q);
            wf[q] = v.x; wf[q+1] = v.y; wf[q+2] = v.z; wf[q+3] = v.w;
        }
#pragma unroll
        for (int y = 0; y < 4; y++)
#pragma unroll
        for (int x = 0; x < 4; x++) {
            float a = acc[y * 4 + x];
#pragma unroll
            for (int ky = 0; ky < 4; ky++) {
                int yy = 2 * y - 1 + ky;
                if (yy < 0 || yy > 7) continue;      // folds at compile time
#pragma unroll
                for (int kx = 0; kx < 4; kx++) {
                    int xx = 2 * x - 1 + kx;
                    if (xx < 0 || xx > 7) continue;
                    a += wf[ky * 4 + kx] * ic[yy * 8 + xx];
                }
            }
            acc[y * 4 + x] = a;
        }
    }
    float s = 0.f, s2 = 0.f;
#pragma unroll
    for (int q = 0; q < 16; q++) { s += acc[q]; s2 += acc[q] * acc[q]; }
    float mean, rstd;
    block_stats_256(s, s2, 4096, mean, rstd);

    float* op = out + (size_t)n * 4096;
#pragma unroll
    for (int q = 0; q < 16; q++) {
        int flat = oc * 16 + q;
        float v = (acc[q] - mean) * rstd * g[flat] + bet[flat];
        op[flat] = silu_f(v);
    }
}

// -------- transpose fc_w [256][4096] -> fcwT [4096][256] (LDS-tiled) -------
__global__ __launch_bounds__(256) void trfc_k(const float* __restrict__ w,
                                              float* __restrict__ wt)
{
    __shared__ float t[32][33];
    int bk = blockIdx.x * 32;             // k dim (4096)
    int bj = blockIdx.y * 32;             // j dim (256)
    int lx = threadIdx.x & 31, ly = threadIdx.x >> 5;   // 32 x 8
#pragma unroll
    for (int s = 0; s < 4; s++)
        t[ly + 8*s][lx] = w[(size_t)(bj + ly + 8*s) * 4096 + bk + lx];
    __syncthreads();
#pragma unroll
    for (int s = 0; s < 4; s++)
        wt[(size_t)(bk + ly + 8*s) * 256 + bj + lx] = t[lx][ly + 8*s];
}

// ---------------- fc: [S,4096] @ wT[4096][256], coalesced ------------------
__global__ __launch_bounds__(256) void fc_k2(const float* __restrict__ a,
    const float* __restrict__ wT, const float* __restrict__ bias, float* __restrict__ o)
{
    int n0 = blockIdx.x * 8;              // chunk-local rows
    int j  = threadIdx.x;
    float acc[8];
#pragma unroll
    for (int r = 0; r < 8; r++) acc[r] = 0.f;
    for (int k = 0; k < 4096; k += 4) {
        float wv0 = wT[(size_t)k * 256 + j];
        float wv1 = wT[(size_t)(k+1) * 256 + j];
        float wv2 = wT[(size_t)(k+2) * 256 + j];
        float wv3 = wT[(size_t)(k+3) * 256 + j];
#pragma unroll
        for (int r = 0; r < 8; r++) {
            const float* ar = a + (size_t)(n0 + r) * 4096 + k;   // uniform -> s_load x4
            acc[r] += wv0*ar[0] + wv1*ar[1] + wv2*ar[2] + wv3*ar[3];
        }
    }
    float bj = bias[j];
#pragma unroll
    for (int r = 0; r < 8; r++) o[(size_t)(n0 + r) * 256 + j] = acc[r] + bj;
}

// ----------- Fpost[n,j] = post_b[j] + feats[n,:] @ post_w[j,128:384] -------
__global__ __launch_bounds__(256) void fpost_k(const float* __restrict__ f,
    const float* __restrict__ w, const float* __restrict__ bias, float* __restrict__ o)
{
    int n0 = blockIdx.x * 4;
    int tid = threadIdx.x;
    float acc[4][4];
#pragma unroll
    for (int r = 0; r < 4; r++)
#pragma unroll
        for (int jj = 0; jj < 4; jj++) acc[r][jj] = 0.f;
    for (int k = 0; k < 256; k += 4) {
        float4 wv[4];
#pragma unroll
        for (int jj = 0; jj < 4; jj++)
            wv[jj] = *(const float4*)(w + (size_t)(tid + jj * 256) * 384 + 128 + k);
#pragma unroll
        for (int r = 0; r < 4; r++) {
            const float* fr = f + (size_t)(n0 + r) * 256 + k;    // uniform
            float a0 = fr[0], a1 = fr[1], a2 = fr[2], a3 = fr[3];
#pragma unroll
            for (int jj = 0; jj < 4; jj++)
                acc[r][jj] += wv[jj].x*a0 + wv[jj].y*a1 + wv[jj].z*a2 + wv[jj].w*a3;
        }
    }
#pragma unroll
    for (int jj = 0; jj < 4; jj++) {
        float bj = bias[tid + jj * 256];
#pragma unroll
        for (int r = 0; r < 4; r++)
            o[(size_t)(n0 + r) * 1024 + tid + jj * 256] = acc[r][jj] + bj;
    }
}

// ----------- prior[n,j] = prior_b[j] + h[n,:] @ prior_w[j,:] ---------------
__global__ __launch_bounds__(256) void prior_k(const float* __restrict__ h,
    const float* __restrict__ w, const float* __restrict__ bias, float* __restrict__ o)
{
    int n0 = blockIdx.x * 4;
    int tid = threadIdx.x;
    float acc[4][4];
#pragma unroll
    for (int r = 0; r < 4; r++)
#pragma unroll
        for (int jj = 0; jj < 4; jj++) acc[r][jj] = 0.f;
    for (int k = 0; k < 128; k += 4) {
        float4 wv[4];
#pragma unroll
        for (int jj = 0; jj < 4; jj++)
            wv[jj] = *(const float4*)(w + (size_t)(tid + jj * 256) * 128 + k);
#pragma unroll
        for (int r = 0; r < 4; r++) {
            const float* hr = h + (size_t)(n0 + r) * 128 + k;    // uniform
            float a0 = hr[0], a1 = hr[1], a2 = hr[2], a3 = hr[3];
#pragma unroll
            for (int jj = 0; jj < 4; jj++)
                acc[r][jj] += wv[jj].x*a0 + wv[jj].y*a1 + wv[jj].z*a2 + wv[jj].w*a3;
        }
    }
#pragma unroll
    for (int jj = 0; jj < 4; jj++) {
        float bj = bias[tid + jj * 256];
#pragma unroll
        for (int r = 0; r < 4; r++)
            o[(size_t)(n0 + r) * 1024 + tid + jj * 256] = acc[r][jj] + bj;
    }
}

// ----------- Ai[n,j] = bih[j] + actions[n,:] @ wih[j,1024:1030] ------------
__global__ __launch_bounds__(128) void ai_k(const float* __restrict__ act,
    const float* __restrict__ wih, const float* __restrict__ bih, float* __restrict__ o)
{
    int n = blockIdx.x;
    int j = blockIdx.y * 128 + threadIdx.x;     // 0..383
    const float* ar = act + (size_t)n * 6;       // uniform
    const float* wr = wih + (size_t)j * 1030 + 1024;
    float acc = bih[j];
#pragma unroll
    for (int k = 0; k < 6; k++) acc += ar[k] * wr[k];
    o[(size_t)n * 384 + j] = acc;
}

// ----------- wihT[k,j] = wih[j,k]  (z-part only, k<1024) -------------------
__global__ __launch_bounds__(256) void tr_k(const float* __restrict__ wih,
                                            float* __restrict__ wt)
{
    int g = blockIdx.x * 256 + threadIdx.x;      // 0..393215
    int k = g / 384;
    int j = g - k * 384;
    wt[g] = wih[(size_t)j * 1030 + k];
}

// ------------------------- GRU recurrence (1 block / sample) ---------------
__global__ __launch_bounds__(1024) void gru_k(const float* __restrict__ wihT,
    const float* __restrict__ whh, const float* __restrict__ bhh,
    const float* __restrict__ ai, const float* __restrict__ fpost,
    const float* __restrict__ postw, float* __restrict__ out)
{
    float* out_post = out + 1048576;
    float* out_h    = out + 2097152;
    float* out_z    = out + 2228224;
    int b   = blockIdx.x;
    int tid = threadIdx.x;
    __shared__ __align__(16) float h[128];
    __shared__ float gi[384], gh[384], p[1024];
    __shared__ int idx[32];
    if (tid < 128) h[tid] = 0.f;
    __syncthreads();

    for (int t = 0; t < 64; t++) {
        int n = b * 64 + t;
        if (tid < 384) {
            float a = ai[(size_t)n * 384 + tid];
            if (t > 0) {
#pragma unroll 8
                for (int c = 0; c < 32; c++)
                    a += wihT[(size_t)(c * 32 + idx[c]) * 384 + tid];
            }
            gi[tid] = a;
            float a2 = bhh[tid];
            const float* wr = whh + (size_t)tid * 128;
#pragma unroll
            for (int k = 0; k < 128; k += 4) {
                float4 wv = *(const float4*)(wr + k);
                float4 hv = *(const float4*)(h + k);
                a2 += wv.x*hv.x + wv.y*hv.y + wv.z*hv.z + wv.w*hv.w;
            }
            gh[tid] = a2;
        }
        __syncthreads();                                    // B1
        if (tid < 128) {
            float r  = sigm_f(gi[tid] + gh[tid]);
            float u  = sigm_f(gi[128 + tid] + gh[128 + tid]);
            float nn = tanhf(gi[256 + tid] + r * gh[256 + tid]);
            float hn = (1.f - u) * nn + u * h[tid];
            h[tid] = hn;
            out_h[(size_t)n * 128 + tid] = hn;
        }
        __syncthreads();                                    // B2
        {
            float a = fpost[(size_t)n * 1024 + tid];
            const float* wr = postw + (size_t)tid * 384;
#pragma unroll
            for (int k = 0; k < 128; k += 4) {
                float4 wv = *(const float4*)(wr + k);
                float4 hv = *(const float4*)(h + k);
                a += wv.x*hv.x + wv.y*hv.y + wv.z*hv.z + wv.w*hv.w;
            }
            p[tid] = a;
            out_post[(size_t)n * 1024 + tid] = a;
        }
        __syncthreads();                                    // B3
        if (tid < 32) {
            const float* pc = p + tid * 32;
            float best = pc[0]; int bi = 0;
#pragma unroll
            for (int q = 1; q < 32; q++) {
                float v = pc[q];
                if (v > best) { best = v; bi = q; }         // first-max = np.argmax
            }
            idx[tid] = bi;
        }
        __syncthreads();                                    // B4
        out_z[(size_t)n * 1024 + tid] = ((tid & 31) == idx[tid >> 5]) ? 1.f : 0.f;
    }
}

// ---------------------------------------------------------------------------
extern "C" void kernel_launch(void* const* d_in, const int* in_sizes, int n_in,
                              void* d_out, int out_size, void* d_ws, size_t ws_size,
                              hipStream_t stream)
{
    const float* states  = (const float*)d_in[0];
    const float* actions = (const float*)d_in[1];
    const float* c1w = (const float*)d_in[2];  const float* c1b = (const float*)d_in[3];
    const float* l1g = (const float*)d_in[4];  const float* l1b = (const float*)d_in[5];
    const float* c2w = (const float*)d_in[6];  const float* c2b = (const float*)d_in[7];
    const float* l2g = (const float*)d_in[8];  const float* l2b = (const float*)d_in[9];
    const float* c3w = (const float*)d_in[10]; const float* c3b = (const float*)d_in[11];
    const float* l3g = (const float*)d_in[12]; const float* l3b = (const float*)d_in[13];
    const float* c4w = (const float*)d_in[14]; const float* c4b = (const float*)d_in[15];
    const float* l4g = (const float*)d_in[16]; const float* l4b = (const float*)d_in[17];
    const float* fcw = (const float*)d_in[18]; const float* fcb = (const float*)d_in[19];
    const float* wih = (const float*)d_in[20]; const float* whh = (const float*)d_in[21];
    const float* bih = (const float*)d_in[22]; const float* bhh = (const float*)d_in[23];
    const float* prw = (const float*)d_in[24]; const float* prb = (const float*)d_in[25];
    const float* pw  = (const float*)d_in[26]; const float* pb  = (const float*)d_in[27];

    float* out = (float*)d_out;
    float* ws  = (float*)d_ws;

    // ---- adaptive chunking: largest S whose footprint fits ws_size --------
    // footprint = (S*49152 + fixed 3,145,728) floats
    size_t S = 64;
    {
        const size_t cands[4] = {1024, 512, 256, 128};
        for (int i = 0; i < 4; i++) {
            size_t need = (cands[i] * 49152ull + 3145728ull) * 4ull;
            if (need <= ws_size) { S = cands[i]; break; }
        }
    }
    int C = (int)(1024 / S);

    float* bufA  = ws;                       // S*32768
    float* bufB  = bufA + S * 32768;         // S*16384
    float* feats = bufB + S * 16384;         //   262,144
    float* fpost = feats + 262144;           // 1,048,576
    float* aibuf = fpost + 1048576;          //   393,216
    float* wihT  = aibuf + 393216;           //   393,216
    float* fcwT  = wihT + 393216;            // 1,048,576

    trfc_k<<<dim3(128, 8), 256, 0, stream>>>(fcw, fcwT);

    for (int cc = 0; cc < C; cc++) {
        size_t n0 = (size_t)cc * S;
        conv1_k<<<dim3((unsigned)S, 4), 256, 0, stream>>>(states + n0 * 12288, c1w, c1b, bufA);
        ln_fuse_k<<<(unsigned)S, 256, 0, stream>>>(bufA, l1g, l1b, 32768);
        conv2_r<<<(unsigned)S, 256, 0, stream>>>(bufA, c2w, c2b, bufB);
        ln_fuse_k<<<(unsigned)S, 256, 0, stream>>>(bufB, l2g, l2b, 16384);
        conv3_r<<<(unsigned)S, 256, 0, stream>>>(bufB, c3w, c3b, bufA);
        ln_fuse_k<<<(unsigned)S, 256, 0, stream>>>(bufA, l3g, l3b, 8192);
        conv4_f<<<(unsigned)S, 256, 0, stream>>>(bufA, c4w, c4b, l4g, l4b, bufB);
        fc_k2<<<(unsigned)(S / 8), 256, 0, stream>>>(bufB, fcwT, fcb, feats + n0 * 256);
    }

    fpost_k<<<256, 256, 0, stream>>>(feats, pw, pb, fpost);
    ai_k<<<dim3(1024, 3), 128, 0, stream>>>(actions, wih, bih, aibuf);
    tr_k<<<1536, 256, 0, stream>>>(wih, wihT);

    gru_k<<<16, 1024, 0, stream>>>(wihT, whh, bhh, aibuf, fpost, pw, out);
    prior_k<<<256, 256, 0, stream>>>(out + 2097152, prw, prb, out);
}